// Round 17
// baseline (68.313 us; speedup 1.0000x reference)
//
#include <hip/hip_runtime.h>

#define VOUT_ELEMS 12582912   // 8*128*3*4096

typedef __attribute__((ext_vector_type(8))) short bf16x8;
typedef __attribute__((ext_vector_type(4))) float f32x4;

__device__ __forceinline__ unsigned short f2b(float f) {
  unsigned x = __float_as_uint(f);
  x = (x + 0x7FFFu + ((x >> 16) & 1u)) >> 16;
  return (unsigned short)x;
}
__device__ __forceinline__ float b2f(unsigned short u) {
  return __uint_as_float(((unsigned)u) << 16);
}
__device__ __forceinline__ unsigned pk2(float a, float b) {
  unsigned r;
  asm("v_cvt_pk_bf16_f32 %0, %1, %2" : "=v"(r) : "v"(a), "v"(b));
  return r;
}

// ws layout (bf16 elems): aW1@0, aW2@16384, aFC@32768, aVD@65536, aSV@81920,
// aVS@90112, aSS@98304.
// f32 at byte 204800 (wsf): [0:128) b2n, [128:256) bfcn, [256:384) bdirn,
// [384:512) rs1, [512:640) rs2, [640:768) rsF, [768:896) vdm (already /128).

__global__ void kprep0(const float* __restrict__ weight, const float* __restrict__ cross_w,
                       const float* __restrict__ crossfc_w, const float* __restrict__ vsdir_w,
                       const float* __restrict__ cross_b, const float* __restrict__ crossfc_b,
                       const float* __restrict__ vsdir_b, float* __restrict__ wsf)
{
  const int tid = threadIdx.x;              // 256
  const int l = tid & 63;
  const int wg = blockIdx.x*4 + (tid>>6);   // 0..63, 2 rows each
#pragma unroll
  for (int k = 0; k < 2; ++k) {
    int o = wg*2 + k;
    float a = weight[o*127+l]  + ((l<63) ? weight[o*127+64+l]  : 0.f);
    float b = cross_w[o*127+l] + ((l<63) ? cross_w[o*127+64+l] : 0.f);
    float f = crossfc_w[o*255+l] + crossfc_w[o*255+64+l] + crossfc_w[o*255+128+l]
            + ((l<63) ? crossfc_w[o*255+192+l] : 0.f);
    float v = vsdir_w[o*128+l] + vsdir_w[o*128+64+l];
#pragma unroll
    for (int m = 1; m < 64; m <<= 1) {
      a += __shfl_xor(a,m,64); b += __shfl_xor(b,m,64);
      f += __shfl_xor(f,m,64); v += __shfl_xor(v,m,64);
    }
    if (l == 0) {
      wsf[384+o] = a; wsf[512+o] = b; wsf[640+o] = f; wsf[768+o] = v*(1.f/128.f);
    }
  }
  if (blockIdx.x == 0 && tid < 192) {
    const float* bsrc = (tid < 64) ? cross_b : (tid < 128 ? crossfc_b : vsdir_b);
    float a = 0.f;
    for (int i = l; i < 128; i += 64) { float t = bsrc[i]; a += t*t; }
#pragma unroll
    for (int m = 1; m < 64; m <<= 1) a += __shfl_xor(a,m,64);
    float nb = fmaxf(sqrtf(a), 1e-12f);
    for (int i = l; i < 128; i += 64)
      wsf[(tid>>6)*128 + i] = bsrc[i] / nb * 1e-6f;
  }
}

__global__ void kprep1(const float* __restrict__ weight, const float* __restrict__ sv_w,
                       const float* __restrict__ cross_w, const float* __restrict__ crossfc_w,
                       const float* __restrict__ vsdir_w, const float* __restrict__ vs_w,
                       const float* __restrict__ ss_w,
                       unsigned short* __restrict__ wsb, const float* __restrict__ wsf)
{
  const int stride = 64*256;
  const int base = blockIdx.x*256 + threadIdx.x;
  const float* rs1 = wsf+384; const float* rs2 = wsf+512;
  const float* rsF = wsf+640; const float* vdm = wsf+768;
  for (int i = base; i < 16384; i += stride) {
    int j=i&7, lane=(i>>3)&63, ks=(i>>9)&3, mt=i>>11;
    int o=16*mt+(lane&15), cc=32*ks+8*(lane>>4)+j;
    wsb[i]       = f2b(cc<127 ? weight[o*127+cc]  : 1.f-rs1[o]);
    wsb[16384+i] = f2b(cc<127 ? cross_w[o*127+cc] : 1.f-rs2[o]);
    wsb[65536+i] = f2b(vsdir_w[o*128+cc] - vdm[o]);
  }
  for (int i = base; i < 32768; i += stride) {
    int j=i&7, lane=(i>>3)&63, ks=(i>>9)&7, mt=i>>12;
    int o=16*mt+(lane&15), cc=32*ks+8*(lane>>4)+j;
    wsb[32768+i] = f2b(cc<255 ? crossfc_w[o*255+cc] : 1.f-rsF[o]);
  }
  for (int i = base; i < 8192; i += stride) {
    int j=i&7, lane=(i>>3)&63, ks=(i>>9)&1, mt=i>>10;
    int o=16*mt+(lane&15), s=32*ks+8*(lane>>4)+j;
    wsb[81920+i] = f2b(sv_w[o*64+s]);
  }
  for (int i = base; i < 8192; i += stride) {
    int j=i&7, lane=(i>>3)&63, ks=(i>>9)&3, mt=i>>11;
    int o=16*mt+(lane&15), c=32*ks+8*(lane>>4)+j;
    wsb[90112+i] = f2b(vs_w[o*128+c]);
  }
  for (int i = base; i < 4096; i += stride) {
    int j=i&7, lane=(i>>3)&63, ks=(i>>9)&1, mt=i>>10;
    int o=16*mt+(lane&15), s=32*ks+8*(lane>>4)+j;
    wsb[98304+i] = f2b(ss_w[o*64+s]);
  }
}

// 512 threads, 8 waves; 16 sites/block; wave w owns ONE M-tile mt=w.
// R13 structure exactly (B1/B2/B2b/B3, two reduction rounds, 40-float acc,
// gmx+gred aliased into bfr xo-slots with B2b fence, stride-12 padded
// reductions). R17 single-knob delta: waves_per_eu(5) — budget 102 regs/wave
// >= ~92 demand (52 arch + 40 acc), so no crush (unlike R10 where demand
// was ~188), and residency rises 4->5 waves/EU.
__global__ __launch_bounds__(512) __attribute__((amdgpu_waves_per_eu(5)))
void kmain(
    const float* __restrict__ v_in, const float* __restrict__ s_in,
    const float* __restrict__ sv_b, const float* __restrict__ vs_b,
    const float* __restrict__ ss_b,
    const unsigned short* __restrict__ wsb, const float* __restrict__ wsf,
    float* __restrict__ out_v, float* __restrict__ out_s)
{
  __shared__ __align__(16) unsigned char smem[33792];
  unsigned short* bfr = (unsigned short*)smem;                  // 24576 B, slots 0..23
  float* gmx          = (float*)(smem + 12288);                 // 192 B  (alias slot 12)
  float (*gred)[16][12] = (float(*)[16][12])(smem + 12480);     // 8*16*12*4 = 6144 B (alias)
  unsigned short* sfr = (unsigned short*)(smem + 24576);        // 2048 B
  unsigned short* vfr = (unsigned short*)(smem + 26624);        // 4096 B
  float (*gred2)[16][12] = (float(*)[16][12])(smem + 30720);    // 4*16*12*4 = 3072 B

  const int tid = threadIdx.x;
  const int w = tid >> 6, l = tid & 63, h = l >> 4, c15 = l & 15;
  const int n0 = blockIdx.x * 16;
  const size_t bb = blockIdx.y;
  const size_t vbase = bb*384*4096 + n0;
  const size_t sbase = bb*64*4096 + n0;

  // ---- phase A: quad-channel pair-packed scatter ----
  if (tid < 384) {                              // (cq 0..31, d 0..2, q 0..3)
    int i = tid;
    int q = i & 3, d = (i >> 2) % 3, cq = i / 12;
    const float* src = &v_in[vbase + (size_t)(4*cq*3 + d)*4096 + 4*q];
    float4 x0 = *(const float4*)(src);
    float4 x1 = *(const float4*)(src + 3*4096);
    float4 x2 = *(const float4*)(src + 6*4096);
    float4 x3 = *(const float4*)(src + 9*4096);
    int slot = (cq >> 3)*3 + d;
    int hh = (cq >> 1) & 3;
    int jp = 2*(cq & 1);
    unsigned* bp = (unsigned*)bfr + (slot*64 + 16*hh + 4*q)*4 + jp;
    float a0[4]={x0.x,x0.y,x0.z,x0.w}, a1[4]={x1.x,x1.y,x1.z,x1.w};
    float a2[4]={x2.x,x2.y,x2.z,x2.w}, a3[4]={x3.x,x3.y,x3.z,x3.w};
#pragma unroll
    for (int e=0;e<4;++e)
      *(uint2*)(bp + e*4) = make_uint2(pk2(a0[e],a1[e]), pk2(a2[e],a3[e]));
  } else if (tid < 448) {                       // (sq 0..15, q 0..3)
    int st = tid - 384;
    int q = st & 3, sq = st >> 2;
    const float* src = &s_in[sbase + (size_t)(4*sq)*4096 + 4*q];
    float4 x0 = *(const float4*)(src);
    float4 x1 = *(const float4*)(src + 4096);
    float4 x2 = *(const float4*)(src + 2*4096);
    float4 x3 = *(const float4*)(src + 3*4096);
    int slot = sq >> 3;
    int hh = (sq >> 1) & 3;
    int jp = 2*(sq & 1);
    unsigned* bp = (unsigned*)sfr + (slot*64 + 16*hh + 4*q)*4 + jp;
    float a0[4]={x0.x,x0.y,x0.z,x0.w}, a1[4]={x1.x,x1.y,x1.z,x1.w};
    float a2[4]={x2.x,x2.y,x2.z,x2.w}, a3[4]={x3.x,x3.y,x3.z,x3.w};
#pragma unroll
    for (int e=0;e<4;++e)
      *(uint2*)(bp + e*4) = make_uint2(pk2(a0[e],a1[e]), pk2(a2[e],a3[e]));
  }
  __syncthreads();  // B1

  const bf16x8* bv  = (const bf16x8*)bfr;
  const bf16x8* sfv_p = (const bf16x8*)sfr;
  const bf16x8* vfv_p = (const bf16x8*)vfr;
  const bf16x8* wv  = (const bf16x8*)wsb;
  const int obA = 16*w + 4*h;          // this wave's output-row base

  // ---- phase B: W1 (avo), W2 (adu), Vdir (adr), sv (asc), ones-GEMV ----
  f32x4 avo[3], adu[3], adr[3], asc;
  {
    f32x4 b2A = *(const f32x4*)&wsf[obA];
    f32x4 bdA = *(const f32x4*)&wsf[256+obA];
#pragma unroll
    for (int d=0;d<3;++d) {
      avo[d]=(f32x4){0.f,0.f,0.f,0.f};
      adu[d]=b2A;
      adr[d]=bdA;
    }
    asc = *(const f32x4*)&sv_b[obA];
  }
#pragma unroll
  for (int ks=0;ks<4;++ks) {
    bf16x8 bx[3];
#pragma unroll
    for (int d=0;d<3;++d) bx[d] = bv[(ks*3+d)*64 + l];
    int fa = w*4 + ks;
    bf16x8 a1 = wv[fa*64 + l];
    bf16x8 a2 = wv[2048 + fa*64 + l];
    bf16x8 a3 = wv[8192 + fa*64 + l];
#pragma unroll
    for (int d=0;d<3;++d) {
      avo[d] = __builtin_amdgcn_mfma_f32_16x16x32_bf16(a1, bx[d], avo[d], 0,0,0);
      adu[d] = __builtin_amdgcn_mfma_f32_16x16x32_bf16(a2, bx[d], adu[d], 0,0,0);
      adr[d] = __builtin_amdgcn_mfma_f32_16x16x32_bf16(a3, bx[d], adr[d], 0,0,0);
    }
  }
#pragma unroll
  for (int ks=0;ks<2;++ks) {
    bf16x8 a4 = wv[10240 + (w*2+ks)*64 + l];
    asc = __builtin_amdgcn_mfma_f32_16x16x32_bf16(a4, sfv_p[ks*64+l], asc, 0,0,0);
  }
  if (w < 3) {  // x channel-mean via ones-row GEMV; wave w handles d=w
    bf16x8 aone;
#pragma unroll
    for (int j=0;j<8;++j) aone[j] = (short)0x3C00;  // bf16(1/128)
    f32x4 amx = (f32x4){0.f,0.f,0.f,0.f};
#pragma unroll
    for (int ks=0;ks<4;++ks)
      amx = __builtin_amdgcn_mfma_f32_16x16x32_bf16(aone, bv[(ks*3+w)*64+l], amx, 0,0,0);
    if (h==0) gmx[16*w + c15] = amx[0];
  }

  // ---- round-1 reductions: pv[3], pd[3], pd2, ps ----
  {
    float red[8];
#pragma unroll
    for (int d=0;d<3;++d) {
      red[d]   = avo[d][0]+avo[d][1]+avo[d][2]+avo[d][3];
      red[3+d] = adu[d][0]+adu[d][1]+adu[d][2]+adu[d][3];
    }
    float q2 = 0.f;
#pragma unroll
    for (int d=0;d<3;++d)
#pragma unroll
      for (int r=0;r<4;++r) q2 += adu[d][r]*adu[d][r];
    red[6] = q2;
    red[7] = asc[0]*asc[0]+asc[1]*asc[1]+asc[2]*asc[2]+asc[3]*asc[3];
#pragma unroll
    for (int m=16;m<64;m<<=1)
#pragma unroll
      for (int i=0;i<8;++i) red[i] += __shfl_xor(red[i], m, 64);
    if (h==0)
#pragma unroll
      for (int i=0;i<8;++i) gred[i][c15][w] = red[i];
  }
  __syncthreads(); // B2

  float mvo[3], mdu[3], mxv[3], d2s, sinv;
#pragma unroll
  for (int d=0;d<3;++d) {
    const f32x4* p  = (const f32x4*)gred[d][c15];
    const f32x4* p2 = (const f32x4*)gred[3+d][c15];
    f32x4 t0=p[0], t1=p[1], u0=p2[0], u1=p2[1];
    mvo[d] = (t0[0]+t0[1]+t0[2]+t0[3]+t1[0]+t1[1]+t1[2]+t1[3]) * (1.f/128.f);
    mdu[d] = (u0[0]+u0[1]+u0[2]+u0[3]+u1[0]+u1[1]+u1[2]+u1[3]) * (1.f/128.f);
    mxv[d] = gmx[16*d + c15];
  }
  { const f32x4* p = (const f32x4*)gred[6][c15];
    f32x4 t0=p[0], t1=p[1];
    d2s = t0[0]+t0[1]+t0[2]+t0[3]+t1[0]+t1[1]+t1[2]+t1[3]; }
  { const f32x4* p = (const f32x4*)gred[7][c15];
    f32x4 t0=p[0], t1=p[1];
    sinv = 1.f / fmaxf(sqrtf(t0[0]+t0[1]+t0[2]+t0[3]+t1[0]+t1[1]+t1[2]+t1[3]), 1e-12f); }

  // apply invariant scale; po partials
  float po[3] = {0.f,0.f,0.f};
#pragma unroll
  for (int r=0;r<4;++r) {
    float sk = asc[r] * sinv;
#pragma unroll
    for (int d=0;d<3;++d) {
      float t = (avo[d][r]-mvo[d])*sk + mvo[d];
      avo[d][r] = t;
      po[d] += t;
    }
  }

  // v_sR readback (ephemeral) + dir-normalized invariant dot
  const int ksq = w >> 1;
  const int hh2 = 2*(w&1) + (h>>1);
  const int ju = 2*(h&1);
  float sfvv[4]; float pfn = 0.f;
  {
    float xr[3][4];
#pragma unroll
    for (int d=0;d<3;++d) {
      uint2 u = *(const uint2*)((const unsigned*)bfr + ((ksq*3+d)*64 + 16*hh2 + c15)*4 + ju);
      xr[d][0]=b2f((unsigned short)u.x);  xr[d][1]=b2f((unsigned short)(u.x>>16));
      xr[d][2]=b2f((unsigned short)u.y);  xr[d][3]=b2f((unsigned short)(u.y>>16));
    }
#pragma unroll
    for (int r=0;r<4;++r) {
      float dx=adr[0][r], dy=adr[1][r], dz=adr[2][r];
      float rn = sqrtf(dx*dx+dy*dy+dz*dz);
      float inv = 1.f/fmaxf(rn,1e-12f);
      float vx = xr[0][r]-mxv[0], vy = xr[1][r]-mxv[1], vz = xr[2][r]-mxv[2];
      float dot = (vx*dx+vy*dy+vz*dz)*inv;
      sfvv[r] = dot; pfn += dot*dot;
    }
  }

  // ---- round-2 reductions: po[3], pfn ----
  {
    float red2[4] = {po[0], po[1], po[2], pfn};
#pragma unroll
    for (int m=16;m<64;m<<=1)
#pragma unroll
      for (int i=0;i<4;++i) red2[i] += __shfl_xor(red2[i], m, 64);
    if (h==0)
#pragma unroll
      for (int i=0;i<4;++i) gred2[i][c15][w] = red2[i];
  }
  __syncthreads(); // B2b (fences xr/gmx/gred reads before xd/xo writes)

  float moo[3], sfni;
#pragma unroll
  for (int d=0;d<3;++d) {
    const f32x4* p = (const f32x4*)gred2[d][c15];
    f32x4 t0=p[0], t1=p[1];
    moo[d] = (t0[0]+t0[1]+t0[2]+t0[3]+t1[0]+t1[1]+t1[2]+t1[3]) * (1.f/128.f);
  }
  { const f32x4* p = (const f32x4*)gred2[3][c15];
    f32x4 t0=p[0], t1=p[1];
    sfni = 1.f/fmaxf(sqrtf(t0[0]+t0[1]+t0[2]+t0[3]+t1[0]+t1[1]+t1[2]+t1[3]), 1e-12f); }

  // cross-product + fragment writes (own channels only)
  float m2 = mdu[0]*mdu[0]+mdu[1]*mdu[1]+mdu[2]*mdu[2];
  float F  = sqrtf(fmaxf(d2s - 128.f*m2, 0.f));
  float Fi = 1.f/fmaxf(F, 1e-12f);
  {
    *(uint2*)((unsigned*)vfr + (ksq*64 + 16*hh2 + c15)*4 + ju) =
      make_uint2(pk2(sfvv[0]*sfni, sfvv[1]*sfni),
                 pk2(sfvv[2]*sfni, sfvv[3]*sfni));
    float cv[3][4];
#pragma unroll
    for (int r=0;r<4;++r) {
      float ax=adu[0][r]-mdu[0], ay=adu[1][r]-mdu[1], az=adu[2][r]-mdu[2];
      float rn = sqrtf(ax*ax+ay*ay+az*az);
      float s1 = (rn*Fi)/fmaxf(rn,1e-12f);
      ax*=s1; ay*=s1; az*=s1;
      float bx=avo[0][r]-moo[0], by=avo[1][r]-moo[1], bz=avo[2][r]-moo[2];
      cv[0][r]=ay*bz-az*by+avo[0][r];
      cv[1][r]=az*bx-ax*bz+avo[1][r];
      cv[2][r]=ax*by-ay*bx+avo[2][r];
    }
#pragma unroll
    for (int d=0;d<3;++d) {
      *(uint2*)((unsigned*)bfr + ((ksq*3+d)*64 + 16*hh2 + c15)*4 + ju) =
        make_uint2(pk2(cv[d][0],cv[d][1]), pk2(cv[d][2],cv[d][3]));
      *(uint2*)((unsigned*)bfr + (((4+ksq)*3+d)*64 + 16*hh2 + c15)*4 + ju) =
        make_uint2(pk2(avo[d][0],avo[d][1]), pk2(avo[d][2],avo[d][3]));
    }
  }
  __syncthreads(); // B3

  // ---- phase C: crossfc (K=256) + VS/SS GEMMs (waves 0..3) ----
  f32x4 afc[3];
  {
    f32x4 bfA = *(const f32x4*)&wsf[128+obA];
#pragma unroll
    for (int d=0;d<3;++d) afc[d]=bfA;
  }
#pragma unroll
  for (int ks=0;ks<8;++ks) {
    bf16x8 bx[3];
#pragma unroll
    for (int d=0;d<3;++d) bx[d] = bv[(ks*3+d)*64 + l];
    bf16x8 a5 = wv[4096 + (w*8+ks)*64 + l];
#pragma unroll
    for (int d=0;d<3;++d)
      afc[d] = __builtin_amdgcn_mfma_f32_16x16x32_bf16(a5, bx[d], afc[d], 0,0,0);
  }
  if (w < 4) {
    f32x4 as2;
    {
      f32x4 bv1 = *(const f32x4*)&vs_b[obA];
      f32x4 bv2 = *(const f32x4*)&ss_b[obA];
      as2 = (f32x4){bv1[0]+bv2[0], bv1[1]+bv2[1], bv1[2]+bv2[2], bv1[3]+bv2[3]};
    }
#pragma unroll
    for (int ks=0;ks<4;++ks) {
      bf16x8 a6 = wv[11264 + (w*4+ks)*64 + l];
      as2 = __builtin_amdgcn_mfma_f32_16x16x32_bf16(a6, vfv_p[ks*64+l], as2, 0,0,0);
    }
#pragma unroll
    for (int ks=0;ks<2;++ks) {
      bf16x8 a7 = wv[12288 + (w*2+ks)*64 + l];
      as2 = __builtin_amdgcn_mfma_f32_16x16x32_bf16(a7, sfv_p[ks*64+l], as2, 0,0,0);
    }
#pragma unroll
    for (int r=0;r<4;++r)
      out_s[sbase + (size_t)(obA+r)*4096 + c15] = as2[r];
  }

  // ---- epilogue: direct global stores (v) ----
#pragma unroll
  for (int d=0;d<3;++d)
#pragma unroll
    for (int r=0;r<4;++r)
      out_v[vbase + (size_t)((obA+r)*3 + d)*4096 + c15] = afc[d][r];
}

extern "C" void kernel_launch(void* const* d_in, const int* in_sizes, int n_in,
                              void* d_out, int out_size, void* d_ws, size_t ws_size,
                              hipStream_t stream) {
  (void)in_sizes; (void)n_in; (void)out_size; (void)ws_size;
  const float* v_in      = (const float*)d_in[0];
  const float* s_in      = (const float*)d_in[1];
  const float* weight    = (const float*)d_in[2];
  const float* sv_w      = (const float*)d_in[3];
  const float* sv_b      = (const float*)d_in[4];
  const float* cross_w   = (const float*)d_in[5];
  const float* cross_b   = (const float*)d_in[6];
  const float* crossfc_w = (const float*)d_in[7];
  const float* crossfc_b = (const float*)d_in[8];
  const float* vsdir_w   = (const float*)d_in[9];
  const float* vsdir_b   = (const float*)d_in[10];
  const float* vs_w      = (const float*)d_in[11];
  const float* vs_b      = (const float*)d_in[12];
  const float* ss_w      = (const float*)d_in[13];
  const float* ss_b      = (const float*)d_in[14];

  unsigned short* wsb = (unsigned short*)d_ws;
  float* wsf = (float*)((char*)d_ws + 204800);

  kprep0<<<16, 256, 0, stream>>>(weight, cross_w, crossfc_w, vsdir_w,
                                 cross_b, crossfc_b, vsdir_b, wsf);
  kprep1<<<64, 256, 0, stream>>>(weight, sv_w, cross_w, crossfc_w, vsdir_w,
                                 vs_w, ss_w, wsb, wsf);
  dim3 grid(4096/16, 8);
  kmain<<<grid, 512, 0, stream>>>(v_in, s_in, sv_b, vs_b, ss_b, wsb, wsf,
                                  (float*)d_out, (float*)d_out + VOUT_ELEMS);
}

// Round 18
// 62.838 us; speedup vs baseline: 1.0871x; 1.0871x over previous
//
#include <hip/hip_runtime.h>

#define VOUT_ELEMS 12582912   // 8*128*3*4096

typedef __attribute__((ext_vector_type(8))) short bf16x8;
typedef __attribute__((ext_vector_type(4))) float f32x4;

__device__ __forceinline__ unsigned short f2b(float f) {
  unsigned x = __float_as_uint(f);
  x = (x + 0x7FFFu + ((x >> 16) & 1u)) >> 16;
  return (unsigned short)x;
}
__device__ __forceinline__ float b2f(unsigned short u) {
  return __uint_as_float(((unsigned)u) << 16);
}
__device__ __forceinline__ unsigned pk2(float a, float b) {
  unsigned r;
  asm("v_cvt_pk_bf16_f32 %0, %1, %2" : "=v"(r) : "v"(a), "v"(b));
  return r;
}

// ws layout (bf16 elems): aW1@0, aW2@16384, aFC@32768, aVD@65536, aSV@81920,
// aVS@90112, aSS@98304.
// f32 at byte 204800 (wsf): [0:128) b2n, [128:256) bfcn, [256:384) bdirn,
// [384:512) rs1, [512:640) rs2, [640:768) rsF, [768:896) vdm (already /128).

__global__ void kprep0(const float* __restrict__ weight, const float* __restrict__ cross_w,
                       const float* __restrict__ crossfc_w, const float* __restrict__ vsdir_w,
                       const float* __restrict__ cross_b, const float* __restrict__ crossfc_b,
                       const float* __restrict__ vsdir_b, float* __restrict__ wsf)
{
  const int tid = threadIdx.x;              // 256
  const int l = tid & 63;
  const int wg = blockIdx.x*4 + (tid>>6);   // 0..63, 2 rows each
#pragma unroll
  for (int k = 0; k < 2; ++k) {
    int o = wg*2 + k;
    float a = weight[o*127+l]  + ((l<63) ? weight[o*127+64+l]  : 0.f);
    float b = cross_w[o*127+l] + ((l<63) ? cross_w[o*127+64+l] : 0.f);
    float f = crossfc_w[o*255+l] + crossfc_w[o*255+64+l] + crossfc_w[o*255+128+l]
            + ((l<63) ? crossfc_w[o*255+192+l] : 0.f);
    float v = vsdir_w[o*128+l] + vsdir_w[o*128+64+l];
#pragma unroll
    for (int m = 1; m < 64; m <<= 1) {
      a += __shfl_xor(a,m,64); b += __shfl_xor(b,m,64);
      f += __shfl_xor(f,m,64); v += __shfl_xor(v,m,64);
    }
    if (l == 0) {
      wsf[384+o] = a; wsf[512+o] = b; wsf[640+o] = f; wsf[768+o] = v*(1.f/128.f);
    }
  }
  if (blockIdx.x == 0 && tid < 192) {
    const float* bsrc = (tid < 64) ? cross_b : (tid < 128 ? crossfc_b : vsdir_b);
    float a = 0.f;
    for (int i = l; i < 128; i += 64) { float t = bsrc[i]; a += t*t; }
#pragma unroll
    for (int m = 1; m < 64; m <<= 1) a += __shfl_xor(a,m,64);
    float nb = fmaxf(sqrtf(a), 1e-12f);
    for (int i = l; i < 128; i += 64)
      wsf[(tid>>6)*128 + i] = bsrc[i] / nb * 1e-6f;
  }
}

__global__ void kprep1(const float* __restrict__ weight, const float* __restrict__ sv_w,
                       const float* __restrict__ cross_w, const float* __restrict__ crossfc_w,
                       const float* __restrict__ vsdir_w, const float* __restrict__ vs_w,
                       const float* __restrict__ ss_w,
                       unsigned short* __restrict__ wsb, const float* __restrict__ wsf)
{
  const int stride = 64*256;
  const int base = blockIdx.x*256 + threadIdx.x;
  const float* rs1 = wsf+384; const float* rs2 = wsf+512;
  const float* rsF = wsf+640; const float* vdm = wsf+768;
  for (int i = base; i < 16384; i += stride) {
    int j=i&7, lane=(i>>3)&63, ks=(i>>9)&3, mt=i>>11;
    int o=16*mt+(lane&15), cc=32*ks+8*(lane>>4)+j;
    wsb[i]       = f2b(cc<127 ? weight[o*127+cc]  : 1.f-rs1[o]);
    wsb[16384+i] = f2b(cc<127 ? cross_w[o*127+cc] : 1.f-rs2[o]);
    wsb[65536+i] = f2b(vsdir_w[o*128+cc] - vdm[o]);
  }
  for (int i = base; i < 32768; i += stride) {
    int j=i&7, lane=(i>>3)&63, ks=(i>>9)&7, mt=i>>12;
    int o=16*mt+(lane&15), cc=32*ks+8*(lane>>4)+j;
    wsb[32768+i] = f2b(cc<255 ? crossfc_w[o*255+cc] : 1.f-rsF[o]);
  }
  for (int i = base; i < 8192; i += stride) {
    int j=i&7, lane=(i>>3)&63, ks=(i>>9)&1, mt=i>>10;
    int o=16*mt+(lane&15), s=32*ks+8*(lane>>4)+j;
    wsb[81920+i] = f2b(sv_w[o*64+s]);
  }
  for (int i = base; i < 8192; i += stride) {
    int j=i&7, lane=(i>>3)&63, ks=(i>>9)&3, mt=i>>11;
    int o=16*mt+(lane&15), c=32*ks+8*(lane>>4)+j;
    wsb[90112+i] = f2b(vs_w[o*128+c]);
  }
  for (int i = base; i < 4096; i += stride) {
    int j=i&7, lane=(i>>3)&63, ks=(i>>9)&1, mt=i>>10;
    int o=16*mt+(lane&15), s=32*ks+8*(lane>>4)+j;
    wsb[98304+i] = f2b(ss_w[o*64+s]);
  }
}

// 512 threads, 8 waves; 16 sites/block; wave w owns ONE M-tile mt=w.
// R13/R16 structure (B1/B2/B2b/B3, two reduction rounds, 40-float acc,
// amdgpu_waves_per_eu(4), gmx+gred aliased into bfr xo-slots with B2b fence,
// stride-12 padded reductions). FINAL configuration: session best 62.9 us,
// VGPR 52 no-spill, ideal HBM traffic. All tighter register policies
// (R5-R8 cap, R10 (5,5), R17 (5)) and barrier-collapse attempts
// (R12/R14/R15) tripped the allocator crush-to-64/48 + scratch-spill cliff.
__global__ __launch_bounds__(512) __attribute__((amdgpu_waves_per_eu(4)))
void kmain(
    const float* __restrict__ v_in, const float* __restrict__ s_in,
    const float* __restrict__ sv_b, const float* __restrict__ vs_b,
    const float* __restrict__ ss_b,
    const unsigned short* __restrict__ wsb, const float* __restrict__ wsf,
    float* __restrict__ out_v, float* __restrict__ out_s)
{
  __shared__ __align__(16) unsigned char smem[33792];
  unsigned short* bfr = (unsigned short*)smem;                  // 24576 B, slots 0..23
  float* gmx          = (float*)(smem + 12288);                 // 192 B  (alias slot 12)
  float (*gred)[16][12] = (float(*)[16][12])(smem + 12480);     // 8*16*12*4 = 6144 B (alias)
  unsigned short* sfr = (unsigned short*)(smem + 24576);        // 2048 B
  unsigned short* vfr = (unsigned short*)(smem + 26624);        // 4096 B
  float (*gred2)[16][12] = (float(*)[16][12])(smem + 30720);    // 4*16*12*4 = 3072 B

  const int tid = threadIdx.x;
  const int w = tid >> 6, l = tid & 63, h = l >> 4, c15 = l & 15;
  const int n0 = blockIdx.x * 16;
  const size_t bb = blockIdx.y;
  const size_t vbase = bb*384*4096 + n0;
  const size_t sbase = bb*64*4096 + n0;

  // ---- phase A: quad-channel pair-packed scatter ----
  if (tid < 384) {                              // (cq 0..31, d 0..2, q 0..3)
    int i = tid;
    int q = i & 3, d = (i >> 2) % 3, cq = i / 12;
    const float* src = &v_in[vbase + (size_t)(4*cq*3 + d)*4096 + 4*q];
    float4 x0 = *(const float4*)(src);
    float4 x1 = *(const float4*)(src + 3*4096);
    float4 x2 = *(const float4*)(src + 6*4096);
    float4 x3 = *(const float4*)(src + 9*4096);
    int slot = (cq >> 3)*3 + d;
    int hh = (cq >> 1) & 3;
    int jp = 2*(cq & 1);
    unsigned* bp = (unsigned*)bfr + (slot*64 + 16*hh + 4*q)*4 + jp;
    float a0[4]={x0.x,x0.y,x0.z,x0.w}, a1[4]={x1.x,x1.y,x1.z,x1.w};
    float a2[4]={x2.x,x2.y,x2.z,x2.w}, a3[4]={x3.x,x3.y,x3.z,x3.w};
#pragma unroll
    for (int e=0;e<4;++e)
      *(uint2*)(bp + e*4) = make_uint2(pk2(a0[e],a1[e]), pk2(a2[e],a3[e]));
  } else if (tid < 448) {                       // (sq 0..15, q 0..3)
    int st = tid - 384;
    int q = st & 3, sq = st >> 2;
    const float* src = &s_in[sbase + (size_t)(4*sq)*4096 + 4*q];
    float4 x0 = *(const float4*)(src);
    float4 x1 = *(const float4*)(src + 4096);
    float4 x2 = *(const float4*)(src + 2*4096);
    float4 x3 = *(const float4*)(src + 3*4096);
    int slot = sq >> 3;
    int hh = (sq >> 1) & 3;
    int jp = 2*(sq & 1);
    unsigned* bp = (unsigned*)sfr + (slot*64 + 16*hh + 4*q)*4 + jp;
    float a0[4]={x0.x,x0.y,x0.z,x0.w}, a1[4]={x1.x,x1.y,x1.z,x1.w};
    float a2[4]={x2.x,x2.y,x2.z,x2.w}, a3[4]={x3.x,x3.y,x3.z,x3.w};
#pragma unroll
    for (int e=0;e<4;++e)
      *(uint2*)(bp + e*4) = make_uint2(pk2(a0[e],a1[e]), pk2(a2[e],a3[e]));
  }
  __syncthreads();  // B1

  const bf16x8* bv  = (const bf16x8*)bfr;
  const bf16x8* sfv_p = (const bf16x8*)sfr;
  const bf16x8* vfv_p = (const bf16x8*)vfr;
  const bf16x8* wv  = (const bf16x8*)wsb;
  const int obA = 16*w + 4*h;          // this wave's output-row base

  // ---- phase B: W1 (avo), W2 (adu), Vdir (adr), sv (asc), ones-GEMV ----
  f32x4 avo[3], adu[3], adr[3], asc;
  {
    f32x4 b2A = *(const f32x4*)&wsf[obA];
    f32x4 bdA = *(const f32x4*)&wsf[256+obA];
#pragma unroll
    for (int d=0;d<3;++d) {
      avo[d]=(f32x4){0.f,0.f,0.f,0.f};
      adu[d]=b2A;
      adr[d]=bdA;
    }
    asc = *(const f32x4*)&sv_b[obA];
  }
#pragma unroll
  for (int ks=0;ks<4;++ks) {
    bf16x8 bx[3];
#pragma unroll
    for (int d=0;d<3;++d) bx[d] = bv[(ks*3+d)*64 + l];
    int fa = w*4 + ks;
    bf16x8 a1 = wv[fa*64 + l];
    bf16x8 a2 = wv[2048 + fa*64 + l];
    bf16x8 a3 = wv[8192 + fa*64 + l];
#pragma unroll
    for (int d=0;d<3;++d) {
      avo[d] = __builtin_amdgcn_mfma_f32_16x16x32_bf16(a1, bx[d], avo[d], 0,0,0);
      adu[d] = __builtin_amdgcn_mfma_f32_16x16x32_bf16(a2, bx[d], adu[d], 0,0,0);
      adr[d] = __builtin_amdgcn_mfma_f32_16x16x32_bf16(a3, bx[d], adr[d], 0,0,0);
    }
  }
#pragma unroll
  for (int ks=0;ks<2;++ks) {
    bf16x8 a4 = wv[10240 + (w*2+ks)*64 + l];
    asc = __builtin_amdgcn_mfma_f32_16x16x32_bf16(a4, sfv_p[ks*64+l], asc, 0,0,0);
  }
  if (w < 3) {  // x channel-mean via ones-row GEMV; wave w handles d=w
    bf16x8 aone;
#pragma unroll
    for (int j=0;j<8;++j) aone[j] = (short)0x3C00;  // bf16(1/128)
    f32x4 amx = (f32x4){0.f,0.f,0.f,0.f};
#pragma unroll
    for (int ks=0;ks<4;++ks)
      amx = __builtin_amdgcn_mfma_f32_16x16x32_bf16(aone, bv[(ks*3+w)*64+l], amx, 0,0,0);
    if (h==0) gmx[16*w + c15] = amx[0];
  }

  // ---- round-1 reductions: pv[3], pd[3], pd2, ps ----
  {
    float red[8];
#pragma unroll
    for (int d=0;d<3;++d) {
      red[d]   = avo[d][0]+avo[d][1]+avo[d][2]+avo[d][3];
      red[3+d] = adu[d][0]+adu[d][1]+adu[d][2]+adu[d][3];
    }
    float q2 = 0.f;
#pragma unroll
    for (int d=0;d<3;++d)
#pragma unroll
      for (int r=0;r<4;++r) q2 += adu[d][r]*adu[d][r];
    red[6] = q2;
    red[7] = asc[0]*asc[0]+asc[1]*asc[1]+asc[2]*asc[2]+asc[3]*asc[3];
#pragma unroll
    for (int m=16;m<64;m<<=1)
#pragma unroll
      for (int i=0;i<8;++i) red[i] += __shfl_xor(red[i], m, 64);
    if (h==0)
#pragma unroll
      for (int i=0;i<8;++i) gred[i][c15][w] = red[i];
  }
  __syncthreads(); // B2

  float mvo[3], mdu[3], mxv[3], d2s, sinv;
#pragma unroll
  for (int d=0;d<3;++d) {
    const f32x4* p  = (const f32x4*)gred[d][c15];
    const f32x4* p2 = (const f32x4*)gred[3+d][c15];
    f32x4 t0=p[0], t1=p[1], u0=p2[0], u1=p2[1];
    mvo[d] = (t0[0]+t0[1]+t0[2]+t0[3]+t1[0]+t1[1]+t1[2]+t1[3]) * (1.f/128.f);
    mdu[d] = (u0[0]+u0[1]+u0[2]+u0[3]+u1[0]+u1[1]+u1[2]+u1[3]) * (1.f/128.f);
    mxv[d] = gmx[16*d + c15];
  }
  { const f32x4* p = (const f32x4*)gred[6][c15];
    f32x4 t0=p[0], t1=p[1];
    d2s = t0[0]+t0[1]+t0[2]+t0[3]+t1[0]+t1[1]+t1[2]+t1[3]; }
  { const f32x4* p = (const f32x4*)gred[7][c15];
    f32x4 t0=p[0], t1=p[1];
    sinv = 1.f / fmaxf(sqrtf(t0[0]+t0[1]+t0[2]+t0[3]+t1[0]+t1[1]+t1[2]+t1[3]), 1e-12f); }

  // apply invariant scale; po partials
  float po[3] = {0.f,0.f,0.f};
#pragma unroll
  for (int r=0;r<4;++r) {
    float sk = asc[r] * sinv;
#pragma unroll
    for (int d=0;d<3;++d) {
      float t = (avo[d][r]-mvo[d])*sk + mvo[d];
      avo[d][r] = t;
      po[d] += t;
    }
  }

  // v_sR readback (ephemeral) + dir-normalized invariant dot
  const int ksq = w >> 1;
  const int hh2 = 2*(w&1) + (h>>1);
  const int ju = 2*(h&1);
  float sfvv[4]; float pfn = 0.f;
  {
    float xr[3][4];
#pragma unroll
    for (int d=0;d<3;++d) {
      uint2 u = *(const uint2*)((const unsigned*)bfr + ((ksq*3+d)*64 + 16*hh2 + c15)*4 + ju);
      xr[d][0]=b2f((unsigned short)u.x);  xr[d][1]=b2f((unsigned short)(u.x>>16));
      xr[d][2]=b2f((unsigned short)u.y);  xr[d][3]=b2f((unsigned short)(u.y>>16));
    }
#pragma unroll
    for (int r=0;r<4;++r) {
      float dx=adr[0][r], dy=adr[1][r], dz=adr[2][r];
      float rn = sqrtf(dx*dx+dy*dy+dz*dz);
      float inv = 1.f/fmaxf(rn,1e-12f);
      float vx = xr[0][r]-mxv[0], vy = xr[1][r]-mxv[1], vz = xr[2][r]-mxv[2];
      float dot = (vx*dx+vy*dy+vz*dz)*inv;
      sfvv[r] = dot; pfn += dot*dot;
    }
  }

  // ---- round-2 reductions: po[3], pfn ----
  {
    float red2[4] = {po[0], po[1], po[2], pfn};
#pragma unroll
    for (int m=16;m<64;m<<=1)
#pragma unroll
      for (int i=0;i<4;++i) red2[i] += __shfl_xor(red2[i], m, 64);
    if (h==0)
#pragma unroll
      for (int i=0;i<4;++i) gred2[i][c15][w] = red2[i];
  }
  __syncthreads(); // B2b (fences xr/gmx/gred reads before xd/xo writes)

  float moo[3], sfni;
#pragma unroll
  for (int d=0;d<3;++d) {
    const f32x4* p = (const f32x4*)gred2[d][c15];
    f32x4 t0=p[0], t1=p[1];
    moo[d] = (t0[0]+t0[1]+t0[2]+t0[3]+t1[0]+t1[1]+t1[2]+t1[3]) * (1.f/128.f);
  }
  { const f32x4* p = (const f32x4*)gred2[3][c15];
    f32x4 t0=p[0], t1=p[1];
    sfni = 1.f/fmaxf(sqrtf(t0[0]+t0[1]+t0[2]+t0[3]+t1[0]+t1[1]+t1[2]+t1[3]), 1e-12f); }

  // cross-product + fragment writes (own channels only)
  float m2 = mdu[0]*mdu[0]+mdu[1]*mdu[1]+mdu[2]*mdu[2];
  float F  = sqrtf(fmaxf(d2s - 128.f*m2, 0.f));
  float Fi = 1.f/fmaxf(F, 1e-12f);
  {
    *(uint2*)((unsigned*)vfr + (ksq*64 + 16*hh2 + c15)*4 + ju) =
      make_uint2(pk2(sfvv[0]*sfni, sfvv[1]*sfni),
                 pk2(sfvv[2]*sfni, sfvv[3]*sfni));
    float cv[3][4];
#pragma unroll
    for (int r=0;r<4;++r) {
      float ax=adu[0][r]-mdu[0], ay=adu[1][r]-mdu[1], az=adu[2][r]-mdu[2];
      float rn = sqrtf(ax*ax+ay*ay+az*az);
      float s1 = (rn*Fi)/fmaxf(rn,1e-12f);
      ax*=s1; ay*=s1; az*=s1;
      float bx=avo[0][r]-moo[0], by=avo[1][r]-moo[1], bz=avo[2][r]-moo[2];
      cv[0][r]=ay*bz-az*by+avo[0][r];
      cv[1][r]=az*bx-ax*bz+avo[1][r];
      cv[2][r]=ax*by-ay*bx+avo[2][r];
    }
#pragma unroll
    for (int d=0;d<3;++d) {
      *(uint2*)((unsigned*)bfr + ((ksq*3+d)*64 + 16*hh2 + c15)*4 + ju) =
        make_uint2(pk2(cv[d][0],cv[d][1]), pk2(cv[d][2],cv[d][3]));
      *(uint2*)((unsigned*)bfr + (((4+ksq)*3+d)*64 + 16*hh2 + c15)*4 + ju) =
        make_uint2(pk2(avo[d][0],avo[d][1]), pk2(avo[d][2],avo[d][3]));
    }
  }
  __syncthreads(); // B3

  // ---- phase C: crossfc (K=256) + VS/SS GEMMs (waves 0..3) ----
  f32x4 afc[3];
  {
    f32x4 bfA = *(const f32x4*)&wsf[128+obA];
#pragma unroll
    for (int d=0;d<3;++d) afc[d]=bfA;
  }
#pragma unroll
  for (int ks=0;ks<8;++ks) {
    bf16x8 bx[3];
#pragma unroll
    for (int d=0;d<3;++d) bx[d] = bv[(ks*3+d)*64 + l];
    bf16x8 a5 = wv[4096 + (w*8+ks)*64 + l];
#pragma unroll
    for (int d=0;d<3;++d)
      afc[d] = __builtin_amdgcn_mfma_f32_16x16x32_bf16(a5, bx[d], afc[d], 0,0,0);
  }
  if (w < 4) {
    f32x4 as2;
    {
      f32x4 bv1 = *(const f32x4*)&vs_b[obA];
      f32x4 bv2 = *(const f32x4*)&ss_b[obA];
      as2 = (f32x4){bv1[0]+bv2[0], bv1[1]+bv2[1], bv1[2]+bv2[2], bv1[3]+bv2[3]};
    }
#pragma unroll
    for (int ks=0;ks<4;++ks) {
      bf16x8 a6 = wv[11264 + (w*4+ks)*64 + l];
      as2 = __builtin_amdgcn_mfma_f32_16x16x32_bf16(a6, vfv_p[ks*64+l], as2, 0,0,0);
    }
#pragma unroll
    for (int ks=0;ks<2;++ks) {
      bf16x8 a7 = wv[12288 + (w*2+ks)*64 + l];
      as2 = __builtin_amdgcn_mfma_f32_16x16x32_bf16(a7, sfv_p[ks*64+l], as2, 0,0,0);
    }
#pragma unroll
    for (int r=0;r<4;++r)
      out_s[sbase + (size_t)(obA+r)*4096 + c15] = as2[r];
  }

  // ---- epilogue: direct global stores (v) ----
#pragma unroll
  for (int d=0;d<3;++d)
#pragma unroll
    for (int r=0;r<4;++r)
      out_v[vbase + (size_t)((obA+r)*3 + d)*4096 + c15] = afc[d][r];
}

extern "C" void kernel_launch(void* const* d_in, const int* in_sizes, int n_in,
                              void* d_out, int out_size, void* d_ws, size_t ws_size,
                              hipStream_t stream) {
  (void)in_sizes; (void)n_in; (void)out_size; (void)ws_size;
  const float* v_in      = (const float*)d_in[0];
  const float* s_in      = (const float*)d_in[1];
  const float* weight    = (const float*)d_in[2];
  const float* sv_w      = (const float*)d_in[3];
  const float* sv_b      = (const float*)d_in[4];
  const float* cross_w   = (const float*)d_in[5];
  const float* cross_b   = (const float*)d_in[6];
  const float* crossfc_w = (const float*)d_in[7];
  const float* crossfc_b = (const float*)d_in[8];
  const float* vsdir_w   = (const float*)d_in[9];
  const float* vsdir_b   = (const float*)d_in[10];
  const float* vs_w      = (const float*)d_in[11];
  const float* vs_b      = (const float*)d_in[12];
  const float* ss_w      = (const float*)d_in[13];
  const float* ss_b      = (const float*)d_in[14];

  unsigned short* wsb = (unsigned short*)d_ws;
  float* wsf = (float*)((char*)d_ws + 204800);

  kprep0<<<16, 256, 0, stream>>>(weight, cross_w, crossfc_w, vsdir_w,
                                 cross_b, crossfc_b, vsdir_b, wsf);
  kprep1<<<64, 256, 0, stream>>>(weight, sv_w, cross_w, crossfc_w, vsdir_w,
                                 vs_w, ss_w, wsb, wsf);
  dim3 grid(4096/16, 8);
  kmain<<<grid, 512, 0, stream>>>(v_in, s_in, sv_b, vs_b, ss_b, wsb, wsf,
                                  (float*)d_out, (float*)d_out + VOUT_ELEMS);
}